// Round 11
// baseline (5205.824 us; speedup 1.0000x reference)
//
#include <hip/hip_runtime.h>
#include <math.h>

#define NS 512
#define NE 2048
#define NB 64
#define NT 512

// out[c][r] = in[r][c]; rows, cols multiples of 32
__global__ __launch_bounds__(256) void transpose_k(const float* __restrict__ in,
                                                   float* __restrict__ out,
                                                   int rows, int cols) {
  __shared__ float tile[32][33];
  int c0 = blockIdx.x * 32;
  int r0 = blockIdx.y * 32;
  int tx = threadIdx.x;  // 0..31
  int ty = threadIdx.y;  // 0..7
#pragma unroll
  for (int k = 0; k < 32; k += 8) {
    tile[ty + k][tx] = in[(size_t)(r0 + ty + k) * cols + (c0 + tx)];
  }
  __syncthreads();
#pragma unroll
  for (int k = 0; k < 32; k += 8) {
    out[(size_t)(c0 + ty + k) * rows + (r0 + tx)] = tile[tx][ty + k];
  }
}

// Forward, 2-batch 8-member skewed column-slice. Grid 256 = 32 groups x 8
// members (bid = g + 32*m -> all members of a group on one XCD). Member m owns
// columns [64m, 64m+64) for batches bA=g and bB=g+32. Thread (oct=tid>>6,
// jl=tid&63) covers i-block ib=(m+oct)&7, column j=64m+jl for both batches.
// Per iteration (= one timestep for BOTH batches):
//   top: T-slice -> tt[64] regs (port stream overlaps sync chain; asm fence
//        pins issue order), emission prefetch
//   pollA (wave0, ONE 64-lane relaxed load of all 8 flags + __all, 1 acquire)
//   gatherA (1 relaxed agent load/thread) -> computeA -> [pollB by wave0]
//   EA: wave0 reduces/publishes A + releases A-flag  || gatherB (all threads)
//   computeB -> EB: wave0 publishes B + releases B-flag
// Skew => each release->poll gap ~ half an iteration => flag propagation
// (~2400cy) is hidden; polls hit on first try in steady state.
// Exchange medium = time-indexed checkpoint v[t] (write-once). Flags monotonic.
__global__ __launch_bounds__(512, 2) void viterbi_fwd(
    const int* __restrict__ obs,     // [NB][NT]
    const float* __restrict__ start, // [NS]
    const float* __restrict__ trans, // [NS][NS]
    const float* __restrict__ emT,   // [NE][NS]
    float* __restrict__ v,           // [NT][NB][NS] checkpoints + exchange
    int* __restrict__ flags)         // [32][16], zeroed before launch
{
  const int g = blockIdx.x & 31;
  const int m = blockIdx.x >> 5;       // member 0..7
  const int tid = threadIdx.x;
  const int jl = tid & 63;
  const int oct = tid >> 6;            // wave id 0..7
  const int ib = (m + oct) & 7;        // absolute i-block this thread covers
  const int j = m * 64 + jl;           // my output column
  const int bA = g;
  const int bB = g + 32;

  __shared__ __align__(16) float vfA[NS];
  __shared__ __align__(16) float vfB[NS];
  __shared__ float pA[8][64];
  __shared__ float pB[8][64];
  __shared__ int obsA[NT];
  __shared__ int obsB[NT];

  obsA[tid] = obs[bA * NT + tid];
  obsB[tid] = obs[bB * NT + tid];

  // t = 0: all threads compute full v0 for both batches; member 0 checkpoints.
  {
    int oA = obs[bA * NT];
    int oB = obs[bB * NT];
    float a = start[tid] + emT[(size_t)oA * NS + tid];
    float b = start[tid] + emT[(size_t)oB * NS + tid];
    vfA[tid] = a;
    vfB[tid] = b;
    if (m == 0) {
      v[(size_t)bA * NS + tid] = a;
      v[(size_t)bB * NS + tid] = b;
    }
  }
  __syncthreads();

  int* fl = flags + g * 16;  // words 0..7 = A flags, 8..15 = B flags
  const float* tp = trans + (size_t)(ib * 64) * NS + j;

  for (int t = 1; t < NT; ++t) {
    // emission prefetch (wave 0 consumes at EA/EB)
    float eA = 0.f, eB = 0.f;
    if (tid < 64) {
      eA = emT[(size_t)obsA[t] * NS + m * 64 + tid];
      eB = emT[(size_t)obsB[t] * NS + m * 64 + tid];
    }
    // T-slice loads: issued at iteration top so the 2048cy port stream
    // overlaps the sync chain; fence stops the compiler sinking them to use.
    float tt[64];
#pragma unroll
    for (int k = 0; k < 64; ++k) tt[k] = tp[(size_t)k * NS];
    asm volatile("" ::: "memory");

    if (t >= 2) {
      // ---- poll A flags(t-1): one vector load, all 8 flags in one line ----
      if (oct == 0) {
        const int tgt = t - 1;
        for (;;) {
          int f = __hip_atomic_load(fl + (tid & 7), __ATOMIC_RELAXED, __HIP_MEMORY_SCOPE_AGENT);
          if (__all(f >= tgt)) break;
          __builtin_amdgcn_s_sleep(1);
        }
        (void)__hip_atomic_load(fl, __ATOMIC_ACQUIRE, __HIP_MEMORY_SCOPE_AGENT);
      }
      __syncthreads();
      // ---- gather A: remote slices of v[t-1][bA] (1 load/thread) ----
      if (tid < 448) {
        int r = tid >> 6;                // 0..6
        int p = (m + 1 + r) & 7;
        int o = tid & 63;
        float ga = __hip_atomic_load(v + ((size_t)(t - 1) * NB + bA) * NS + p * 64 + o,
                                     __ATOMIC_RELAXED, __HIP_MEMORY_SCOPE_AGENT);
        vfA[p * 64 + o] = ga;
      }
      __syncthreads();
    }

    // ---- compute A (register T + broadcast LDS reads) ----
    {
      float a0 = -INFINITY, a1 = -INFINITY;
      const float4* va = reinterpret_cast<const float4*>(vfA + ib * 64);
#pragma unroll
      for (int c = 0; c < 16; ++c) {
        float4 x = va[c];
        a0 = fmaxf(a0, fmaxf(x.x + tt[4 * c + 0], x.y + tt[4 * c + 1]));
        a1 = fmaxf(a1, fmaxf(x.z + tt[4 * c + 2], x.w + tt[4 * c + 3]));
      }
      pA[oct][jl] = fmaxf(a0, a1);
    }
    // ---- poll B flags(t-1) by wave 0 while other waves drain to barrier ----
    if (t >= 2 && oct == 0) {
      const int tgt = t - 1;
      for (;;) {
        int f = __hip_atomic_load(fl + 8 + (tid & 7), __ATOMIC_RELAXED, __HIP_MEMORY_SCOPE_AGENT);
        if (__all(f >= tgt)) break;
        __builtin_amdgcn_s_sleep(1);
      }
      (void)__hip_atomic_load(fl + 8, __ATOMIC_ACQUIRE, __HIP_MEMORY_SCOPE_AGENT);
    }
    __syncthreads();

    // ---- EA (wave 0) + gather B (all threads) ----
    if (tid < 64) {
      float vn = fmaxf(fmaxf(fmaxf(pA[0][tid], pA[1][tid]), fmaxf(pA[2][tid], pA[3][tid])),
                       fmaxf(fmaxf(pA[4][tid], pA[5][tid]), fmaxf(pA[6][tid], pA[7][tid]))) + eA;
      vfA[m * 64 + tid] = vn;
      __hip_atomic_store(v + ((size_t)t * NB + bA) * NS + m * 64 + tid, vn,
                         __ATOMIC_RELAXED, __HIP_MEMORY_SCOPE_AGENT);
      if (tid == 0)
        __hip_atomic_store(fl + m, t, __ATOMIC_RELEASE, __HIP_MEMORY_SCOPE_AGENT);
    }
    if (t >= 2 && tid < 448) {
      int r = tid >> 6;
      int p = (m + 1 + r) & 7;
      int o = tid & 63;
      float gb = __hip_atomic_load(v + ((size_t)(t - 1) * NB + bB) * NS + p * 64 + o,
                                   __ATOMIC_RELAXED, __HIP_MEMORY_SCOPE_AGENT);
      vfB[p * 64 + o] = gb;
    }
    __syncthreads();

    // ---- compute B ----
    {
      float b0 = -INFINITY, b1 = -INFINITY;
      const float4* vb = reinterpret_cast<const float4*>(vfB + ib * 64);
#pragma unroll
      for (int c = 0; c < 16; ++c) {
        float4 x = vb[c];
        b0 = fmaxf(b0, fmaxf(x.x + tt[4 * c + 0], x.y + tt[4 * c + 1]));
        b1 = fmaxf(b1, fmaxf(x.z + tt[4 * c + 2], x.w + tt[4 * c + 3]));
      }
      pB[oct][jl] = fmaxf(b0, b1);
    }
    __syncthreads();

    // ---- EB (wave 0) ----
    if (tid < 64) {
      float vn = fmaxf(fmaxf(fmaxf(pB[0][tid], pB[1][tid]), fmaxf(pB[2][tid], pB[3][tid])),
                       fmaxf(fmaxf(pB[4][tid], pB[5][tid]), fmaxf(pB[6][tid], pB[7][tid]))) + eB;
      vfB[m * 64 + tid] = vn;
      __hip_atomic_store(v + ((size_t)t * NB + bB) * NS + m * 64 + tid, vn,
                         __ATOMIC_RELAXED, __HIP_MEMORY_SCOPE_AGENT);
      if (tid == 0)
        __hip_atomic_store(fl + 8 + m, t, __ATOMIC_RELEASE, __HIP_MEMORY_SCOPE_AGENT);
    }
    __syncthreads();
  }
}

// Backtrace: one wave per batch; recompute argmax with exact first-wins ties.
__global__ __launch_bounds__(64) void viterbi_bt(
    const float* __restrict__ v,      // [NT][NB][NS]
    const float* __restrict__ transT, // [NS][NS], transT[j][i] = trans[i][j]
    int* __restrict__ path)           // [NB][NT] int32
{
  const int b = blockIdx.x;
  const int lane = threadIdx.x;

  const float4* vrow = reinterpret_cast<const float4*>(v + ((size_t)(NT - 1) * NB + b) * NS);
  float val = -INFINITY;
  int idx = 0;
#pragma unroll
  for (int w = 0; w < 2; ++w) {
    float4 a = vrow[lane + 64 * w];
    int base = 4 * (lane + 64 * w);
    if (a.x > val) { val = a.x; idx = base + 0; }
    if (a.y > val) { val = a.y; idx = base + 1; }
    if (a.z > val) { val = a.z; idx = base + 2; }
    if (a.w > val) { val = a.w; idx = base + 3; }
  }
#pragma unroll
  for (int off = 32; off; off >>= 1) {
    float v2 = __shfl_down(val, off);
    int i2 = __shfl_down(idx, off);
    if (v2 > val || (v2 == val && i2 < idx)) { val = v2; idx = i2; }
  }
  int state = __shfl(idx, 0);
  if (lane == 0) path[b * NT + (NT - 1)] = state;

  float4 vp0, vp1;
  {
    const float4* vp = reinterpret_cast<const float4*>(v + ((size_t)(NT - 2) * NB + b) * NS);
    vp0 = vp[lane];
    vp1 = vp[lane + 64];
  }

  for (int t = NT - 1; t >= 1; --t) {
    float4 np0, np1;
    if (t >= 2) {
      const float4* vp = reinterpret_cast<const float4*>(v + ((size_t)(t - 2) * NB + b) * NS);
      np0 = vp[lane];
      np1 = vp[lane + 64];
    }
    const float4* tr = reinterpret_cast<const float4*>(transT + (size_t)state * NS);
    float4 t0 = tr[lane];
    float4 t1 = tr[lane + 64];

    float val2 = -INFINITY;
    int idx2 = 0;
    {
      float s0 = vp0.x + t0.x, s1 = vp0.y + t0.y, s2 = vp0.z + t0.z, s3 = vp0.w + t0.w;
      int base = 4 * lane;
      if (s0 > val2) { val2 = s0; idx2 = base + 0; }
      if (s1 > val2) { val2 = s1; idx2 = base + 1; }
      if (s2 > val2) { val2 = s2; idx2 = base + 2; }
      if (s3 > val2) { val2 = s3; idx2 = base + 3; }
    }
    {
      float s0 = vp1.x + t1.x, s1 = vp1.y + t1.y, s2 = vp1.z + t1.z, s3 = vp1.w + t1.w;
      int base = 4 * (lane + 64);
      if (s0 > val2) { val2 = s0; idx2 = base + 0; }
      if (s1 > val2) { val2 = s1; idx2 = base + 1; }
      if (s2 > val2) { val2 = s2; idx2 = base + 2; }
      if (s3 > val2) { val2 = s3; idx2 = base + 3; }
    }
#pragma unroll
    for (int off = 32; off; off >>= 1) {
      float v2 = __shfl_down(val2, off);
      int i2 = __shfl_down(idx2, off);
      if (v2 > val2 || (v2 == val2 && i2 < idx2)) { val2 = v2; idx2 = i2; }
    }
    state = __shfl(idx2, 0);
    if (lane == 0) path[b * NT + (t - 1)] = state;
    vp0 = np0;
    vp1 = np1;
  }
}

extern "C" void kernel_launch(void* const* d_in, const int* in_sizes, int n_in,
                              void* d_out, int out_size, void* d_ws, size_t ws_size,
                              hipStream_t stream) {
  const int* obs = (const int*)d_in[0];       // [64][512]
  const float* start = (const float*)d_in[1]; // [512]
  const float* trans = (const float*)d_in[2]; // [512][512]
  const float* emis = (const float*)d_in[3];  // [512][2048]
  int* path = (int*)d_out;                    // [64][512] int32

  char* ws = (char*)d_ws;
  float* emT = (float*)ws;                           // [2048][512] = 4 MB
  float* transT = (float*)(ws + (4ull << 20));       // [512][512]  = 1 MB
  float* v = (float*)(ws + (5ull << 20));            // [512][64][512] = 64 MB
  int* flags = (int*)(ws + (69ull << 20));           // [32][16] = 2 KB

  hipMemsetAsync(flags, 0, 32 * 16 * sizeof(int), stream);

  dim3 tb(32, 8);
  transpose_k<<<dim3(NE / 32, NS / 32), tb, 0, stream>>>(emis, emT, NS, NE);
  transpose_k<<<dim3(NS / 32, NS / 32), tb, 0, stream>>>(trans, transT, NS, NS);
  viterbi_fwd<<<NB * 4, 512, 0, stream>>>(obs, start, trans, emT, v, flags);
  viterbi_bt<<<NB, 64, 0, stream>>>(v, transT, path);
}